// Round 9
// baseline (4665.189 us; speedup 1.0000x reference)
//
#include <hip/hip_runtime.h>
#include <hip/hip_bf16.h>
#include <stdint.h>

// ---------------- problem constants ----------------
constexpr int E   = 384;
constexpr int DFF = 1536;
constexpr int NH  = 6;
constexpr int HD  = 64;
constexpr int T   = 256;
constexpr int NL  = 6;
constexpr int NV  = 65;
constexpr int BB  = 128;
constexpr int MTOT = BB * T;           // 32768 rows
constexpr int CB  = 32;                // (kept for ws layout compatibility)

typedef __bf16 bf16;
typedef __attribute__((ext_vector_type(8))) __bf16 bf16x8;
typedef __attribute__((ext_vector_type(4))) float floatx4;

// ---------------- generic bf16 GEMM: C = A[M,K] @ Bt[N,K]^T ----------------
// Register-direct (no LDS, no barriers): each wave loads its MFMA fragments
// straight from global; compiler pipelines loads with fine-grained vmcnt.
// MODE 0: bf16 out (+bias opt, +relu opt, N-mask via Nvalid)
// MODE 1: f32 residual in-place: C[r,c] += acc + bias
// MODE 4: f32 out with bias + N-mask (final logits)
// MODE 5: fused QKV: cols 0..767 -> qk row-major (ld 768); cols 768..1151 ->
//         vt[(row>>8)*(E*T) + (col-768)*T + (row&255)]  (V transposed store)
#define GBM 128
#define GBN 128
#define GBK 32

template <int MODE, int TK>
__global__ __launch_bounds__(256) void k_gemm(
    const bf16* __restrict__ A, long sAb, long sAh, int lda,
    const bf16* __restrict__ Bt, long sBb, long sBh, int ldb,
    const float* __restrict__ bias,
    void* __restrict__ Cv, void* __restrict__ Cv2, long sCb, long sCh, int ldc,
    int Mtiles, int Ntiles, int Nvalid,
    int bdiv, float scale, int relu)
{
    // XCD swizzle: physical blocks round-robin XCDs; give each XCD a
    // contiguous logical range so all N-tiles of an M-tile share one L2.
    int nb = gridDim.x;
    int per = nb >> 3;
    int bphys = blockIdx.x;
    int bid = (bphys & 7) * per + (bphys >> 3);

    int nt = bid % Ntiles; bid /= Ntiles;
    int mt = bid % Mtiles;
    int bat = bid / Mtiles;
    int bb = bat / bdiv, bh = bat - bb * bdiv;

    const bf16* Ab = A + (long)bb * sAb + (long)bh * sAh + (long)mt * GBM * lda;
    const bf16* Bb = Bt + (long)bb * sBb + (long)bh * sBh + (long)nt * GBN * ldb;

    int tid = threadIdx.x;
    int lane = tid & 63;
    int wid = tid >> 6;
    int wm = wid >> 1, wn = wid & 1;
    int lq = lane >> 4, lr = lane & 15;

    // fragment base pointers (4 lanes of one lq-quad cover 64B of one row)
    const bf16* Aq = Ab + (long)(wm * 64 + lr) * lda + lq * 8;
    const bf16* Bq = Bb + (long)(wn * 64 + lr) * ldb + lq * 8;

    floatx4 zero = {0.f, 0.f, 0.f, 0.f};
    floatx4 acc[4][4];
#pragma unroll
    for (int i = 0; i < 4; i++)
#pragma unroll
        for (int j = 0; j < 4; j++) acc[i][j] = zero;

    constexpr int nk = TK / GBK;
#pragma unroll 4
    for (int ki = 0; ki < nk; ki++) {
        int koff = ki * GBK;
        bf16x8 af[4], bfr[4];
#pragma unroll
        for (int mi = 0; mi < 4; mi++)
            af[mi] = *(const bf16x8*)(Aq + (long)mi * 16 * lda + koff);
#pragma unroll
        for (int ni = 0; ni < 4; ni++)
            bfr[ni] = *(const bf16x8*)(Bq + (long)ni * 16 * ldb + koff);
#pragma unroll
        for (int mi = 0; mi < 4; mi++)
#pragma unroll
            for (int ni = 0; ni < 4; ni++)
                acc[mi][ni] = __builtin_amdgcn_mfma_f32_16x16x32_bf16(
                    af[mi], bfr[ni], acc[mi][ni], 0, 0, 0);
    }

    int m0 = mt * GBM, n0 = nt * GBN;
#pragma unroll
    for (int mi = 0; mi < 4; mi++) {
#pragma unroll
        for (int ni = 0; ni < 4; ni++) {
            int colL = n0 + wn * 64 + ni * 16 + lr;
#pragma unroll
            for (int r = 0; r < 4; r++) {
                int rowL = m0 + wm * 64 + mi * 16 + lq * 4 + r;
                float val = acc[mi][ni][r];
                if (MODE == 5) {
                    val += bias[colL];
                    if (colL < 768) {
                        bf16* Cp = (bf16*)Cv;
                        Cp[(long)rowL * 768 + colL] = (bf16)val;
                    } else {
                        bf16* Cp = (bf16*)Cv2;
                        long addr = (long)(rowL >> 8) * (E * T) + (long)(colL - 768) * T + (rowL & 255);
                        Cp[addr] = (bf16)val;
                    }
                } else if (MODE == 1) {
                    float* Cp = (float*)Cv;
                    long idx = (long)rowL * ldc + colL;
                    Cp[idx] = Cp[idx] + val + bias[colL];
                } else if (MODE == 4) {
                    if (colL < Nvalid) {
                        float* Cp = (float*)Cv;
                        Cp[(long)rowL * ldc + colL] = val + bias[colL];
                    }
                } else {
                    if (colL < Nvalid) {
                        if (bias) val += bias[colL];
                        if (relu) val = fmaxf(val, 0.f);
                        bf16* Cp = (bf16*)Cv + (long)bb * sCb + (long)bh * sCh;
                        Cp[(long)rowL * ldc + colL] = (bf16)val;
                    }
                }
            }
        }
    }
}

// ---------------- fused causal attention ----------------
// grid: (b, h, qt) = BB*NH*4 blocks of 256 threads (4 waves).
__global__ __launch_bounds__(256) void k_attn(
    const bf16* __restrict__ qk, const bf16* __restrict__ vt,
    bf16* __restrict__ o)
{
    int bid = blockIdx.x;
    int qt = bid & 3; bid >>= 2;
    int h = bid % NH; int b = bid / NH;
    int tid = threadIdx.x;
    int lane = tid & 63;
    int w = tid >> 6;
    int lq = lane >> 4;     // 0..3
    int lr = lane & 15;

    __shared__ bf16 P[4][16][264];   // wave-private, +8 pad -> 2-way banks

    const bf16* qbase = qk + (long)(b * T + qt * 64 + w * 16) * 768 + h * 64;
    const bf16* kbase = qk + (long)(b * T) * 768 + 384 + h * 64;
    const bf16* vbase = vt + ((long)b * E + h * 64) * T;

    bf16x8 aq0 = *(const bf16x8*)(qbase + (long)lr * 768 + lq * 8);
    bf16x8 aq1 = *(const bf16x8*)(qbase + (long)lr * 768 + 32 + lq * 8);

    const int ntmax = qt * 4 + 3;
    floatx4 zero = {0.f, 0.f, 0.f, 0.f};
    floatx4 s[16];
#pragma unroll
    for (int nt = 0; nt < 16; nt++) s[nt] = zero;

#pragma unroll
    for (int nt = 0; nt < 16; nt++) {
        if (nt <= ntmax) {
            const bf16* kp = kbase + (long)(nt * 16 + lr) * 768 + lq * 8;
            bf16x8 b0 = *(const bf16x8*)(kp);
            bf16x8 b1 = *(const bf16x8*)(kp + 32);
            s[nt] = __builtin_amdgcn_mfma_f32_16x16x32_bf16(aq0, b0, s[nt], 0, 0, 0);
            s[nt] = __builtin_amdgcn_mfma_f32_16x16x32_bf16(aq1, b1, s[nt], 0, 0, 0);
        }
    }

    int trow0 = qt * 64 + w * 16 + lq * 4;
    float m4[4] = {-3e38f, -3e38f, -3e38f, -3e38f};
#pragma unroll
    for (int nt = 0; nt < 16; nt++) {
        if (nt <= ntmax) {
            int tc = nt * 16 + lr;
#pragma unroll
            for (int r = 0; r < 4; r++) {
                float v = s[nt][r] * 0.125f;
                if (tc > trow0 + r) v = -3e38f;
                s[nt][r] = v;
                m4[r] = fmaxf(m4[r], v);
            }
        }
    }
#pragma unroll
    for (int r = 0; r < 4; r++) {
#pragma unroll
        for (int off = 1; off < 16; off <<= 1)
            m4[r] = fmaxf(m4[r], __shfl_xor(m4[r], off, 64));
    }

    float l4[4] = {0.f, 0.f, 0.f, 0.f};
#pragma unroll
    for (int nt = 0; nt < 16; nt++) {
        if (nt <= ntmax) {
#pragma unroll
            for (int r = 0; r < 4; r++) {
                float pv = __expf(s[nt][r] - m4[r]);
                l4[r] += pv;
                P[w][lq * 4 + r][nt * 16 + lr] = (bf16)pv;
            }
        }
    }
#pragma unroll
    for (int r = 0; r < 4; r++) {
#pragma unroll
        for (int off = 1; off < 16; off <<= 1)
            l4[r] += __shfl_xor(l4[r], off, 64);
    }

    floatx4 oacc[4];
#pragma unroll
    for (int nd = 0; nd < 4; nd++) oacc[nd] = zero;
    const int kkmax = 2 * (qt + 1);
#pragma unroll
    for (int kk = 0; kk < 8; kk++) {
        if (kk < kkmax) {
            bf16x8 ap = *(const bf16x8*)(&P[w][lr][kk * 32 + lq * 8]);
#pragma unroll
            for (int nd = 0; nd < 4; nd++) {
                bf16x8 bv = *(const bf16x8*)(vbase + (long)(nd * 16 + lr) * T + kk * 32 + lq * 8);
                oacc[nd] = __builtin_amdgcn_mfma_f32_16x16x32_bf16(ap, bv, oacc[nd], 0, 0, 0);
            }
        }
    }

#pragma unroll
    for (int r = 0; r < 4; r++) {
        float inv = 1.0f / l4[r];
        long rowg = (long)b * T + trow0 + r;
#pragma unroll
        for (int nd = 0; nd < 4; nd++) {
            o[rowg * E + h * 64 + nd * 16 + lr] = (bf16)(oacc[nd][r] * inv);
        }
    }
}

// ---------------- weight transpose f32 -> bf16 (+zero-pad rows) ----------------
__global__ void k_transpose(const float* __restrict__ W, bf16* __restrict__ Wt,
                            int K, int N, int NPAD) {
    long idx = (long)blockIdx.x * 256 + threadIdx.x;
    long per = (long)NPAD * K;
    int l = (int)(idx / per);
    long r = idx - (long)l * per;
    int n = (int)(r / K);
    int k = (int)(r - (long)n * K);
    Wt[idx] = (n < N) ? (bf16)W[((long)l * K + k) * N + n] : (bf16)0.0f;
}

// ---------------- fused QKV weight transpose: [L][1152][384] ----------------
__global__ void k_transpose_qkv(const float* __restrict__ Wq, const float* __restrict__ Wk,
                                const float* __restrict__ Wv, bf16* __restrict__ Wt) {
    long idx = (long)blockIdx.x * 256 + threadIdx.x;
    long per = (long)1152 * E;
    int l = (int)(idx / per);
    long r = idx - (long)l * per;
    int n = (int)(r / E);
    int k = (int)(r - (long)n * E);
    const float* src;
    int nn;
    if (n < 384)      { src = Wq; nn = n; }
    else if (n < 768) { src = Wk; nn = n - 384; }
    else              { src = Wv; nn = n - 768; }
    Wt[idx] = (bf16)src[((long)l * E + k) * E + nn];
}

// ---------------- fused QKV bias concat: [L][1152] f32 ----------------
__global__ void k_bias_qkv(const float* __restrict__ bq, const float* __restrict__ bk,
                           const float* __restrict__ bv, float* __restrict__ bqkv) {
    int idx = blockIdx.x * 256 + threadIdx.x;
    int l = idx / 1152;
    int j = idx - l * 1152;
    const float* src;
    int jj;
    if (j < 384)      { src = bq; jj = j; }
    else if (j < 768) { src = bk; jj = j - 384; }
    else              { src = bv; jj = j - 768; }
    bqkv[idx] = src[l * E + jj];
}

// ---------------- embedding + positional (f32) ----------------
__global__ void k_embed(const int* __restrict__ tokens, const float* __restrict__ pos,
                        const float* __restrict__ emb, float* __restrict__ x) {
    long idx = (long)blockIdx.x * 256 + threadIdx.x;
    int e = (int)(idx % E);
    long bt = idx / E;
    int t = (int)(bt % T);
    int tok = tokens[bt];
    x[idx] = emb[(long)tok * E + e] + pos[(long)t * E + e];
}

// ---------------- layernorm: f32 in -> bf16 out (wave per row) ----------------
__global__ void k_ln(const float* __restrict__ x, const float* __restrict__ g,
                     const float* __restrict__ b, bf16* __restrict__ h) {
    int row = blockIdx.x * 4 + (threadIdx.x >> 6);
    int lane = threadIdx.x & 63;
    const float* xr = x + (long)row * E;
    float v[6];
    float s = 0.f;
#pragma unroll
    for (int i = 0; i < 6; i++) { v[i] = xr[lane + 64 * i]; s += v[i]; }
#pragma unroll
    for (int o = 1; o < 64; o <<= 1) s += __shfl_xor(s, o, 64);
    float mu = s * (1.0f / E);
    float q = 0.f;
#pragma unroll
    for (int i = 0; i < 6; i++) { float d = v[i] - mu; q += d * d; }
#pragma unroll
    for (int o = 1; o < 64; o <<= 1) q += __shfl_xor(q, o, 64);
    float rs = rsqrtf(q * (1.0f / E) + 1e-5f);
    bf16* hr = h + (long)row * E;
#pragma unroll
    for (int i = 0; i < 6; i++) {
        int c = lane + 64 * i;
        hr[c] = (bf16)((v[i] - mu) * rs * g[c] + b[c]);
    }
}

// ---------------- f32 -> bf16 convert ----------------
__global__ void k_cvt(const float* __restrict__ x, bf16* __restrict__ y) {
    long i = (long)blockIdx.x * 256 + threadIdx.x;
    y[i] = (bf16)x[i];
}

// ---------------- launcher ----------------
extern "C" void kernel_launch(void* const* d_in, const int* in_sizes, int n_in,
                              void* d_out, int out_size, void* d_ws, size_t ws_size,
                              hipStream_t stream) {
    const int*   tokens = (const int*)d_in[0];
    const float* pos  = (const float*)d_in[1];
    const float* emb  = (const float*)d_in[2];
    const float* Wq   = (const float*)d_in[3];
    const float* bq   = (const float*)d_in[4];
    const float* Wk   = (const float*)d_in[5];
    const float* bk   = (const float*)d_in[6];
    const float* Wv   = (const float*)d_in[7];
    const float* bv   = (const float*)d_in[8];
    const float* Wo   = (const float*)d_in[9];
    const float* bo   = (const float*)d_in[10];
    const float* g1   = (const float*)d_in[11];
    const float* be1  = (const float*)d_in[12];
    const float* W1   = (const float*)d_in[13];
    const float* c1   = (const float*)d_in[14];
    const float* W2   = (const float*)d_in[15];
    const float* c2   = (const float*)d_in[16];
    const float* g2   = (const float*)d_in[17];
    const float* be2  = (const float*)d_in[18];
    const float* Wl   = (const float*)d_in[19];
    const float* bl   = (const float*)d_in[20];

    // ---- workspace layout (~198 MB peak; unchanged from r8 which passed) ----
    char* p = (char*)d_ws;
    float* x = (float*)p;  p += (long)MTOT * E * 4;          // residual (f32)
    bf16* h  = (bf16*)p;   p += (long)MTOT * E * 2;          // LN out / o (alias)
    bf16* qk = (bf16*)p;   p += (long)MTOT * 768 * 2;        // fused Q|K
    bf16* vt = (bf16*)p;   p += (long)BB * E * T * 2;        // V^T per (seq,head)
    bf16* SP = (bf16*)p;   p += (long)CB * NH * T * T * 2;   // kept only for mid alias span
    bf16* WqkvT = (bf16*)p; p += (long)NL * 1152 * E * 2;
    bf16* WoT = (bf16*)p;  p += (long)NL * E * E * 2;
    bf16* W1T = (bf16*)p;  p += (long)NL * DFF * E * 2;
    bf16* W2T = (bf16*)p;  p += (long)NL * E * DFF * 2;
    bf16* WlT = (bf16*)p;  p += (long)128 * E * 2;
    float* bqkv = (float*)p; p += (long)NL * 1152 * 4;
    bf16* mid = qk;          // alias: qk+vt+SP = 100.66 MB = MTOT*DFF*2 exactly
    bf16* o   = h;           // alias: h dead after QKV GEMM
    (void)SP;

    // ---- setup (once per call) ----
    k_transpose_qkv<<<(NL * 1152 * E) / 256, 256, 0, stream>>>(Wq, Wk, Wv, WqkvT);
    k_transpose<<<(NL * E * E) / 256, 256, 0, stream>>>(Wo, WoT, E, E, E);
    k_transpose<<<(NL * DFF * E) / 256, 256, 0, stream>>>(W1, W1T, E, DFF, DFF);
    k_transpose<<<(NL * E * DFF) / 256, 256, 0, stream>>>(W2, W2T, DFF, E, E);
    k_transpose<<<(128 * E) / 256, 256, 0, stream>>>(Wl, WlT, E, NV, 128);
    k_bias_qkv<<<(NL * 1152) / 256, 256, 0, stream>>>(bq, bk, bv, bqkv);

    // ---- embedding ----
    k_embed<<<(MTOT * E) / 256, 256, 0, stream>>>(tokens, pos, emb, x);

    for (int l = 0; l < NL; l++) {
        // LN1 full-M
        k_ln<<<MTOT / 4, 256, 0, stream>>>(x, g1 + l * E, be1 + l * E, h);
        // fused QKV: M=32768, N=1152, K=384
        k_gemm<5, 384><<<256 * 9, 256, 0, stream>>>(h, 0, 0, E, WqkvT + (long)l * 1152 * E, 0, 0, E,
                                                    bqkv + l * 1152, qk, vt, 0, 0, 0,
                                                    256, 9, 1152, 1, 1.0f, 0);
        // fused causal attention: one dispatch
        k_attn<<<BB * NH * 4, 256, 0, stream>>>(qk, vt, o);
        // x += O @ Wo + bo   (f32 in-place, full-M)
        k_gemm<1, 384><<<256 * 3, 256, 0, stream>>>(o, 0, 0, E, WoT + (long)l * E * E, 0, 0, E,
                                                    bo + l * E, x, nullptr, 0, 0, E,
                                                    256, 3, E, 1, 1.0f, 0);
        // LN2 full-M
        k_ln<<<MTOT / 4, 256, 0, stream>>>(x, g2 + l * E, be2 + l * E, h);
        // mid = relu(h @ W1 + c1)   (M=32768, N=1536)
        k_gemm<0, 384><<<256 * 12, 256, 0, stream>>>(h, 0, 0, E, W1T + (long)l * DFF * E, 0, 0, E,
                                                     c1 + l * DFF, mid, nullptr, 0, 0, DFF,
                                                     256, 12, DFF, 1, 1.0f, 1);
        // x += mid @ W2 + c2   (K=1536)
        k_gemm<1, 1536><<<256 * 3, 256, 0, stream>>>(mid, 0, 0, DFF, W2T + (long)l * E * DFF, 0, 0, DFF,
                                                     c2 + l * E, x, nullptr, 0, 0, E,
                                                     256, 3, E, 1, 1.0f, 0);
    }

    // logits = x_bf16 @ Wl + bl  (N=65 masked from 128), f32 out, full-M
    k_cvt<<<(MTOT * E) / 256, 256, 0, stream>>>(x, h);
    k_gemm<4, 384><<<256 * 1, 256, 0, stream>>>(h, 0, 0, E, WlT, 0, 0, E,
                                                bl, d_out, nullptr, 0, 0, NV,
                                                256, 1, NV, 1, 1.0f, 0);
}

// Round 10
// 2502.195 us; speedup vs baseline: 1.8644x; 1.8644x over previous
//
#include <hip/hip_runtime.h>
#include <hip/hip_bf16.h>
#include <stdint.h>

// ---------------- problem constants ----------------
constexpr int E   = 384;
constexpr int DFF = 1536;
constexpr int NH  = 6;
constexpr int HD  = 64;
constexpr int T   = 256;
constexpr int NL  = 6;
constexpr int NV  = 65;
constexpr int BB  = 128;
constexpr int MTOT = BB * T;           // 32768 rows
constexpr int CB  = 32;                // (kept for ws layout compatibility)

typedef __bf16 bf16;
typedef __attribute__((ext_vector_type(8))) __bf16 bf16x8;
typedef __attribute__((ext_vector_type(4))) float floatx4;

// ---------------- generic bf16 GEMM: C = A[M,K] @ Bt[N,K]^T ----------------
// Two-step staging pipeline (prefetch distance 2):
//   iter k: ds_write tile k+1 (regs loaded at k-1), issue reg-load tile k+2,
//           compute tile k from LDS, barrier.
// vmcnt waits attach to ds_write (one iter after load issue), not the barrier.
// MODE 0: bf16 out (+bias opt, +relu opt, N-mask via Nvalid)
// MODE 1: f32 residual in-place: C[r,c] += acc + bias
// MODE 4: f32 out with bias + N-mask (final logits)
// MODE 5: fused QKV: cols 0..767 -> qk row-major (ld 768); cols 768..1151 ->
//         vt[(row>>8)*(E*T) + (col-768)*T + (row&255)]  (V transposed store)
#define GBM 128
#define GBN 128
#define GBK 32

template <int MODE>
__global__ __launch_bounds__(256) void k_gemm(
    const bf16* __restrict__ A, long sAb, long sAh, int lda,
    const bf16* __restrict__ Bt, long sBb, long sBh, int ldb,
    const float* __restrict__ bias,
    void* __restrict__ Cv, void* __restrict__ Cv2, long sCb, long sCh, int ldc,
    int Mtiles, int Ntiles, int Nvalid, int K,
    int bdiv, float scale, int relu)
{
    __shared__ __align__(16) bf16 As[2 * GBM * GBK];   // 2 x 8 KB
    __shared__ __align__(16) bf16 Bs[2 * GBN * GBK];

    // XCD swizzle: all N-tiles of an M-tile land on one XCD's L2.
    int nb = gridDim.x;
    int per = nb >> 3;
    int bphys = blockIdx.x;
    int bid = (bphys & 7) * per + (bphys >> 3);

    int nt = bid % Ntiles; bid /= Ntiles;
    int mt = bid % Mtiles;
    int bat = bid / Mtiles;
    int bb = bat / bdiv, bh = bat - bb * bdiv;

    const bf16* Ab = A + (long)bb * sAb + (long)bh * sAh + (long)mt * GBM * lda;
    const bf16* Bb = Bt + (long)bb * sBb + (long)bh * sBh + (long)nt * GBN * ldb;

    int tid = threadIdx.x;
    int lane = tid & 63;
    int wid = tid >> 6;
    int wm = wid >> 1, wn = wid & 1;
    int lq = lane >> 4, lr = lane & 15;

    int srow = tid >> 2;            // 0..63
    int skc  = (tid & 3) * 8;       // k element offset 0,8,16,24

    const bf16* Arow = Ab + (long)srow * lda + skc;
    const bf16* Brow = Bb + (long)srow * ldb + skc;
    const long a2 = 64 * (long)lda;
    const long b2 = 64 * (long)ldb;

    char* AsB = (char*)As;
    char* BsB = (char*)Bs;

    floatx4 zero = {0.f, 0.f, 0.f, 0.f};
    floatx4 acc[4][4];
#pragma unroll
    for (int i = 0; i < 4; i++)
#pragma unroll
        for (int j = 0; j < 4; j++) acc[i][j] = zero;

    int nk = K / GBK;

    // prologue: tile0 -> regs -> buf0; tile1 -> regs
    bf16x8 ra0 = *(const bf16x8*)(Arow);
    bf16x8 ra1 = *(const bf16x8*)(Arow + a2);
    bf16x8 rb0 = *(const bf16x8*)(Brow);
    bf16x8 rb1 = *(const bf16x8*)(Brow + b2);
    *(bf16x8*)(AsB + tid * 16)        = ra0;
    *(bf16x8*)(AsB + 4096 + tid * 16) = ra1;
    *(bf16x8*)(BsB + tid * 16)        = rb0;
    *(bf16x8*)(BsB + 4096 + tid * 16) = rb1;
    if (nk > 1) {
        ra0 = *(const bf16x8*)(Arow + GBK);
        ra1 = *(const bf16x8*)(Arow + a2 + GBK);
        rb0 = *(const bf16x8*)(Brow + GBK);
        rb1 = *(const bf16x8*)(Brow + b2 + GBK);
    }
    __syncthreads();

    for (int ki = 0; ki < nk; ki++) {
        int ib = ki & 1;
        if (ki + 1 < nk) {
            // write tile ki+1 (regs loaded one iter ago) into the free buffer
            char* An = AsB + (1 - ib) * 8192;
            char* Bn = BsB + (1 - ib) * 8192;
            *(bf16x8*)(An + tid * 16)        = ra0;
            *(bf16x8*)(An + 4096 + tid * 16) = ra1;
            *(bf16x8*)(Bn + tid * 16)        = rb0;
            *(bf16x8*)(Bn + 4096 + tid * 16) = rb1;
        }
        if (ki + 2 < nk) {
            // issue loads for tile ki+2 (2 iterations of latency tolerance)
            int koff = (ki + 2) * GBK;
            ra0 = *(const bf16x8*)(Arow + koff);
            ra1 = *(const bf16x8*)(Arow + a2 + koff);
            rb0 = *(const bf16x8*)(Brow + koff);
            rb1 = *(const bf16x8*)(Brow + b2 + koff);
        }
        char* Ac = AsB + ib * 8192;
        char* Bc = BsB + ib * 8192;

        bf16x8 af[4], bfr[4];
#pragma unroll
        for (int mi = 0; mi < 4; mi++)
            af[mi] = *(const bf16x8*)(Ac + ((wm * 64 + mi * 16 + lr) * GBK + lq * 8) * 2);
#pragma unroll
        for (int ni = 0; ni < 4; ni++)
            bfr[ni] = *(const bf16x8*)(Bc + ((wn * 64 + ni * 16 + lr) * GBK + lq * 8) * 2);
#pragma unroll
        for (int mi = 0; mi < 4; mi++)
#pragma unroll
            for (int ni = 0; ni < 4; ni++)
                acc[mi][ni] = __builtin_amdgcn_mfma_f32_16x16x32_bf16(
                    af[mi], bfr[ni], acc[mi][ni], 0, 0, 0);
        __syncthreads();
    }

    int m0 = mt * GBM, n0 = nt * GBN;
#pragma unroll
    for (int mi = 0; mi < 4; mi++) {
#pragma unroll
        for (int ni = 0; ni < 4; ni++) {
            int colL = n0 + wn * 64 + ni * 16 + lr;
#pragma unroll
            for (int r = 0; r < 4; r++) {
                int rowL = m0 + wm * 64 + mi * 16 + lq * 4 + r;
                float val = acc[mi][ni][r];
                if (MODE == 5) {
                    val += bias[colL];
                    if (colL < 768) {
                        bf16* Cp = (bf16*)Cv;
                        Cp[(long)rowL * 768 + colL] = (bf16)val;
                    } else {
                        bf16* Cp = (bf16*)Cv2;
                        long addr = (long)(rowL >> 8) * (E * T) + (long)(colL - 768) * T + (rowL & 255);
                        Cp[addr] = (bf16)val;
                    }
                } else if (MODE == 1) {
                    float* Cp = (float*)Cv;
                    long idx = (long)rowL * ldc + colL;
                    Cp[idx] = Cp[idx] + val + bias[colL];
                } else if (MODE == 4) {
                    if (colL < Nvalid) {
                        float* Cp = (float*)Cv;
                        Cp[(long)rowL * ldc + colL] = val + bias[colL];
                    }
                } else {
                    if (colL < Nvalid) {
                        if (bias) val += bias[colL];
                        if (relu) val = fmaxf(val, 0.f);
                        bf16* Cp = (bf16*)Cv + (long)bb * sCb + (long)bh * sCh;
                        Cp[(long)rowL * ldc + colL] = (bf16)val;
                    }
                }
            }
        }
    }
}

// ---------------- fused causal attention ----------------
// grid: (b, h, qt) = BB*NH*4 blocks of 256 threads (4 waves).
__global__ __launch_bounds__(256) void k_attn(
    const bf16* __restrict__ qk, const bf16* __restrict__ vt,
    bf16* __restrict__ o)
{
    int bid = blockIdx.x;
    int qt = bid & 3; bid >>= 2;
    int h = bid % NH; int b = bid / NH;
    int tid = threadIdx.x;
    int lane = tid & 63;
    int w = tid >> 6;
    int lq = lane >> 4;     // 0..3
    int lr = lane & 15;

    __shared__ bf16 P[4][16][264];   // wave-private, +8 pad -> 2-way banks

    const bf16* qbase = qk + (long)(b * T + qt * 64 + w * 16) * 768 + h * 64;
    const bf16* kbase = qk + (long)(b * T) * 768 + 384 + h * 64;
    const bf16* vbase = vt + ((long)b * E + h * 64) * T;

    bf16x8 aq0 = *(const bf16x8*)(qbase + (long)lr * 768 + lq * 8);
    bf16x8 aq1 = *(const bf16x8*)(qbase + (long)lr * 768 + 32 + lq * 8);

    const int ntmax = qt * 4 + 3;
    floatx4 zero = {0.f, 0.f, 0.f, 0.f};
    floatx4 s[16];
#pragma unroll
    for (int nt = 0; nt < 16; nt++) s[nt] = zero;

#pragma unroll
    for (int nt = 0; nt < 16; nt++) {
        if (nt <= ntmax) {
            const bf16* kp = kbase + (long)(nt * 16 + lr) * 768 + lq * 8;
            bf16x8 b0 = *(const bf16x8*)(kp);
            bf16x8 b1 = *(const bf16x8*)(kp + 32);
            s[nt] = __builtin_amdgcn_mfma_f32_16x16x32_bf16(aq0, b0, s[nt], 0, 0, 0);
            s[nt] = __builtin_amdgcn_mfma_f32_16x16x32_bf16(aq1, b1, s[nt], 0, 0, 0);
        }
    }

    int trow0 = qt * 64 + w * 16 + lq * 4;
    float m4[4] = {-3e38f, -3e38f, -3e38f, -3e38f};
#pragma unroll
    for (int nt = 0; nt < 16; nt++) {
        if (nt <= ntmax) {
            int tc = nt * 16 + lr;
#pragma unroll
            for (int r = 0; r < 4; r++) {
                float v = s[nt][r] * 0.125f;
                if (tc > trow0 + r) v = -3e38f;
                s[nt][r] = v;
                m4[r] = fmaxf(m4[r], v);
            }
        }
    }
#pragma unroll
    for (int r = 0; r < 4; r++) {
#pragma unroll
        for (int off = 1; off < 16; off <<= 1)
            m4[r] = fmaxf(m4[r], __shfl_xor(m4[r], off, 64));
    }

    float l4[4] = {0.f, 0.f, 0.f, 0.f};
#pragma unroll
    for (int nt = 0; nt < 16; nt++) {
        if (nt <= ntmax) {
#pragma unroll
            for (int r = 0; r < 4; r++) {
                float pv = __expf(s[nt][r] - m4[r]);
                l4[r] += pv;
                P[w][lq * 4 + r][nt * 16 + lr] = (bf16)pv;
            }
        }
    }
#pragma unroll
    for (int r = 0; r < 4; r++) {
#pragma unroll
        for (int off = 1; off < 16; off <<= 1)
            l4[r] += __shfl_xor(l4[r], off, 64);
    }

    floatx4 oacc[4];
#pragma unroll
    for (int nd = 0; nd < 4; nd++) oacc[nd] = zero;
    const int kkmax = 2 * (qt + 1);
#pragma unroll
    for (int kk = 0; kk < 8; kk++) {
        if (kk < kkmax) {
            bf16x8 ap = *(const bf16x8*)(&P[w][lr][kk * 32 + lq * 8]);
#pragma unroll
            for (int nd = 0; nd < 4; nd++) {
                bf16x8 bv = *(const bf16x8*)(vbase + (long)(nd * 16 + lr) * T + kk * 32 + lq * 8);
                oacc[nd] = __builtin_amdgcn_mfma_f32_16x16x32_bf16(ap, bv, oacc[nd], 0, 0, 0);
            }
        }
    }

#pragma unroll
    for (int r = 0; r < 4; r++) {
        float inv = 1.0f / l4[r];
        long rowg = (long)b * T + trow0 + r;
#pragma unroll
        for (int nd = 0; nd < 4; nd++) {
            o[rowg * E + h * 64 + nd * 16 + lr] = (bf16)(oacc[nd][r] * inv);
        }
    }
}

// ---------------- weight transpose f32 -> bf16 (+zero-pad rows) ----------------
__global__ void k_transpose(const float* __restrict__ W, bf16* __restrict__ Wt,
                            int K, int N, int NPAD) {
    long idx = (long)blockIdx.x * 256 + threadIdx.x;
    long per = (long)NPAD * K;
    int l = (int)(idx / per);
    long r = idx - (long)l * per;
    int n = (int)(r / K);
    int k = (int)(r - (long)n * K);
    Wt[idx] = (n < N) ? (bf16)W[((long)l * K + k) * N + n] : (bf16)0.0f;
}

// ---------------- fused QKV weight transpose: [L][1152][384] ----------------
__global__ void k_transpose_qkv(const float* __restrict__ Wq, const float* __restrict__ Wk,
                                const float* __restrict__ Wv, bf16* __restrict__ Wt) {
    long idx = (long)blockIdx.x * 256 + threadIdx.x;
    long per = (long)1152 * E;
    int l = (int)(idx / per);
    long r = idx - (long)l * per;
    int n = (int)(r / E);
    int k = (int)(r - (long)n * E);
    const float* src;
    int nn;
    if (n < 384)      { src = Wq; nn = n; }
    else if (n < 768) { src = Wk; nn = n - 384; }
    else              { src = Wv; nn = n - 768; }
    Wt[idx] = (bf16)src[((long)l * E + k) * E + nn];
}

// ---------------- fused QKV bias concat: [L][1152] f32 ----------------
__global__ void k_bias_qkv(const float* __restrict__ bq, const float* __restrict__ bk,
                           const float* __restrict__ bv, float* __restrict__ bqkv) {
    int idx = blockIdx.x * 256 + threadIdx.x;
    int l = idx / 1152;
    int j = idx - l * 1152;
    const float* src;
    int jj;
    if (j < 384)      { src = bq; jj = j; }
    else if (j < 768) { src = bk; jj = j - 384; }
    else              { src = bv; jj = j - 768; }
    bqkv[idx] = src[l * E + jj];
}

// ---------------- embedding + positional (f32) ----------------
__global__ void k_embed(const int* __restrict__ tokens, const float* __restrict__ pos,
                        const float* __restrict__ emb, float* __restrict__ x) {
    long idx = (long)blockIdx.x * 256 + threadIdx.x;
    int e = (int)(idx % E);
    long bt = idx / E;
    int t = (int)(bt % T);
    int tok = tokens[bt];
    x[idx] = emb[(long)tok * E + e] + pos[(long)t * E + e];
}

// ---------------- layernorm: f32 in -> bf16 out (wave per row) ----------------
__global__ void k_ln(const float* __restrict__ x, const float* __restrict__ g,
                     const float* __restrict__ b, bf16* __restrict__ h) {
    int row = blockIdx.x * 4 + (threadIdx.x >> 6);
    int lane = threadIdx.x & 63;
    const float* xr = x + (long)row * E;
    float v[6];
    float s = 0.f;
#pragma unroll
    for (int i = 0; i < 6; i++) { v[i] = xr[lane + 64 * i]; s += v[i]; }
#pragma unroll
    for (int o = 1; o < 64; o <<= 1) s += __shfl_xor(s, o, 64);
    float mu = s * (1.0f / E);
    float q = 0.f;
#pragma unroll
    for (int i = 0; i < 6; i++) { float d = v[i] - mu; q += d * d; }
#pragma unroll
    for (int o = 1; o < 64; o <<= 1) q += __shfl_xor(q, o, 64);
    float rs = rsqrtf(q * (1.0f / E) + 1e-5f);
    bf16* hr = h + (long)row * E;
#pragma unroll
    for (int i = 0; i < 6; i++) {
        int c = lane + 64 * i;
        hr[c] = (bf16)((v[i] - mu) * rs * g[c] + b[c]);
    }
}

// ---------------- f32 -> bf16 convert ----------------
__global__ void k_cvt(const float* __restrict__ x, bf16* __restrict__ y) {
    long i = (long)blockIdx.x * 256 + threadIdx.x;
    y[i] = (bf16)x[i];
}

// ---------------- launcher ----------------
extern "C" void kernel_launch(void* const* d_in, const int* in_sizes, int n_in,
                              void* d_out, int out_size, void* d_ws, size_t ws_size,
                              hipStream_t stream) {
    const int*   tokens = (const int*)d_in[0];
    const float* pos  = (const float*)d_in[1];
    const float* emb  = (const float*)d_in[2];
    const float* Wq   = (const float*)d_in[3];
    const float* bq   = (const float*)d_in[4];
    const float* Wk   = (const float*)d_in[5];
    const float* bk   = (const float*)d_in[6];
    const float* Wv   = (const float*)d_in[7];
    const float* bv   = (const float*)d_in[8];
    const float* Wo   = (const float*)d_in[9];
    const float* bo   = (const float*)d_in[10];
    const float* g1   = (const float*)d_in[11];
    const float* be1  = (const float*)d_in[12];
    const float* W1   = (const float*)d_in[13];
    const float* c1   = (const float*)d_in[14];
    const float* W2   = (const float*)d_in[15];
    const float* c2   = (const float*)d_in[16];
    const float* g2   = (const float*)d_in[17];
    const float* be2  = (const float*)d_in[18];
    const float* Wl   = (const float*)d_in[19];
    const float* bl   = (const float*)d_in[20];

    // ---- workspace layout (~198 MB peak; unchanged from r8 which passed) ----
    char* p = (char*)d_ws;
    float* x = (float*)p;  p += (long)MTOT * E * 4;          // residual (f32)
    bf16* h  = (bf16*)p;   p += (long)MTOT * E * 2;          // LN out / o (alias)
    bf16* qk = (bf16*)p;   p += (long)MTOT * 768 * 2;        // fused Q|K
    bf16* vt = (bf16*)p;   p += (long)BB * E * T * 2;        // V^T per (seq,head)
    bf16* SP = (bf16*)p;   p += (long)CB * NH * T * T * 2;   // kept only for mid alias span
    bf16* WqkvT = (bf16*)p; p += (long)NL * 1152 * E * 2;
    bf16* WoT = (bf16*)p;  p += (long)NL * E * E * 2;
    bf16* W1T = (bf16*)p;  p += (long)NL * DFF * E * 2;
    bf16* W2T = (bf16*)p;  p += (long)NL * E * DFF * 2;
    bf16* WlT = (bf16*)p;  p += (long)128 * E * 2;
    float* bqkv = (float*)p; p += (long)NL * 1152 * 4;
    bf16* mid = qk;          // alias: qk+vt+SP = 100.66 MB = MTOT*DFF*2 exactly
    bf16* o   = h;           // alias: h dead after QKV GEMM
    (void)SP;

    // ---- setup (once per call) ----
    k_transpose_qkv<<<(NL * 1152 * E) / 256, 256, 0, stream>>>(Wq, Wk, Wv, WqkvT);
    k_transpose<<<(NL * E * E) / 256, 256, 0, stream>>>(Wo, WoT, E, E, E);
    k_transpose<<<(NL * DFF * E) / 256, 256, 0, stream>>>(W1, W1T, E, DFF, DFF);
    k_transpose<<<(NL * E * DFF) / 256, 256, 0, stream>>>(W2, W2T, DFF, E, E);
    k_transpose<<<(128 * E) / 256, 256, 0, stream>>>(Wl, WlT, E, NV, 128);
    k_bias_qkv<<<(NL * 1152) / 256, 256, 0, stream>>>(bq, bk, bv, bqkv);

    // ---- embedding ----
    k_embed<<<(MTOT * E) / 256, 256, 0, stream>>>(tokens, pos, emb, x);

    for (int l = 0; l < NL; l++) {
        // LN1 full-M
        k_ln<<<MTOT / 4, 256, 0, stream>>>(x, g1 + l * E, be1 + l * E, h);
        // fused QKV: M=32768, N=1152, K=384
        k_gemm<5><<<256 * 9, 256, 0, stream>>>(h, 0, 0, E, WqkvT + (long)l * 1152 * E, 0, 0, E,
                                               bqkv + l * 1152, qk, vt, 0, 0, 0,
                                               256, 9, 1152, E, 1, 1.0f, 0);
        // fused causal attention: one dispatch
        k_attn<<<BB * NH * 4, 256, 0, stream>>>(qk, vt, o);
        // x += O @ Wo + bo   (f32 in-place, full-M)
        k_gemm<1><<<256 * 3, 256, 0, stream>>>(o, 0, 0, E, WoT + (long)l * E * E, 0, 0, E,
                                               bo + l * E, x, nullptr, 0, 0, E,
                                               256, 3, E, E, 1, 1.0f, 0);
        // LN2 full-M
        k_ln<<<MTOT / 4, 256, 0, stream>>>(x, g2 + l * E, be2 + l * E, h);
        // mid = relu(h @ W1 + c1)   (M=32768, N=1536)
        k_gemm<0><<<256 * 12, 256, 0, stream>>>(h, 0, 0, E, W1T + (long)l * DFF * E, 0, 0, E,
                                                c1 + l * DFF, mid, nullptr, 0, 0, DFF,
                                                256, 12, DFF, E, 1, 1.0f, 1);
        // x += mid @ W2 + c2   (K=1536)
        k_gemm<1><<<256 * 3, 256, 0, stream>>>(mid, 0, 0, DFF, W2T + (long)l * E * DFF, 0, 0, DFF,
                                               c2 + l * E, x, nullptr, 0, 0, E,
                                               256, 3, E, DFF, 1, 1.0f, 0);
    }

    // logits = x_bf16 @ Wl + bl  (N=65 masked from 128), f32 out, full-M
    k_cvt<<<(MTOT * E) / 256, 256, 0, stream>>>(x, h);
    k_gemm<4><<<256 * 1, 256, 0, stream>>>(h, 0, 0, E, WlT, 0, 0, E,
                                           bl, d_out, nullptr, 0, 0, NV,
                                           256, 1, NV, E, 1, 1.0f, 0);
}

// Round 11
// 2221.155 us; speedup vs baseline: 2.1003x; 1.1265x over previous
//
#include <hip/hip_runtime.h>
#include <hip/hip_bf16.h>
#include <stdint.h>

// ---------------- problem constants ----------------
constexpr int E   = 384;
constexpr int DFF = 1536;
constexpr int NH  = 6;
constexpr int HD  = 64;
constexpr int T   = 256;
constexpr int NL  = 6;
constexpr int NV  = 65;
constexpr int BB  = 128;
constexpr int MTOT = BB * T;           // 32768 rows
constexpr int CB  = 32;                // (kept for ws layout compatibility)

typedef __bf16 bf16;
typedef __attribute__((ext_vector_type(8))) __bf16 bf16x8;
typedef __attribute__((ext_vector_type(4))) float floatx4;

// ---------------- generic bf16 GEMM: C = A[M,K] @ Bt[N,K]^T ----------------
// Two-step staging pipeline (prefetch distance 2): reg-load tile k+2,
// ds_write tile k+1, compute tile k from LDS. vmcnt waits attach to the
// ds_write one iteration after load issue, not to the barrier.
// MODE 0: bf16 out (+bias opt, +relu opt, N-mask via Nvalid)
// MODE 1: f32 residual in-place: C[r,c] += acc + bias
// MODE 4: f32 out with bias + N-mask (final logits)
// MODE 5: fused QKV: cols 0..767 -> qk row-major (ld 768); cols 768..1151 ->
//         vt[(row>>8)*(E*T) + (col-768)*T + (row&255)]  (V transposed store)
#define GBM 128
#define GBN 128
#define GBK 32

template <int MODE>
__global__ __launch_bounds__(256) void k_gemm(
    const bf16* __restrict__ A, long sAb, long sAh, int lda,
    const bf16* __restrict__ Bt, long sBb, long sBh, int ldb,
    const float* __restrict__ bias,
    void* __restrict__ Cv, void* __restrict__ Cv2, long sCb, long sCh, int ldc,
    int Mtiles, int Ntiles, int Nvalid, int K,
    int bdiv, float scale, int relu)
{
    __shared__ __align__(16) bf16 As[2 * GBM * GBK];   // 2 x 8 KB
    __shared__ __align__(16) bf16 Bs[2 * GBN * GBK];

    // XCD swizzle: all N-tiles of an M-tile land on one XCD's L2.
    int nb = gridDim.x;
    int per = nb >> 3;
    int bphys = blockIdx.x;
    int bid = (bphys & 7) * per + (bphys >> 3);

    int nt = bid % Ntiles; bid /= Ntiles;
    int mt = bid % Mtiles;
    int bat = bid / Mtiles;
    int bb = bat / bdiv, bh = bat - bb * bdiv;

    const bf16* Ab = A + (long)bb * sAb + (long)bh * sAh + (long)mt * GBM * lda;
    const bf16* Bb = Bt + (long)bb * sBb + (long)bh * sBh + (long)nt * GBN * ldb;

    int tid = threadIdx.x;
    int lane = tid & 63;
    int wid = tid >> 6;
    int wm = wid >> 1, wn = wid & 1;
    int lq = lane >> 4, lr = lane & 15;

    int srow = tid >> 2;            // 0..63
    int skc  = (tid & 3) * 8;       // k element offset 0,8,16,24

    const bf16* Arow = Ab + (long)srow * lda + skc;
    const bf16* Brow = Bb + (long)srow * ldb + skc;
    const long a2 = 64 * (long)lda;
    const long b2 = 64 * (long)ldb;

    char* AsB = (char*)As;
    char* BsB = (char*)Bs;

    floatx4 zero = {0.f, 0.f, 0.f, 0.f};
    floatx4 acc[4][4];
#pragma unroll
    for (int i = 0; i < 4; i++)
#pragma unroll
        for (int j = 0; j < 4; j++) acc[i][j] = zero;

    int nk = K / GBK;

    // prologue: tile0 -> regs -> buf0; tile1 -> regs
    bf16x8 ra0 = *(const bf16x8*)(Arow);
    bf16x8 ra1 = *(const bf16x8*)(Arow + a2);
    bf16x8 rb0 = *(const bf16x8*)(Brow);
    bf16x8 rb1 = *(const bf16x8*)(Brow + b2);
    *(bf16x8*)(AsB + tid * 16)        = ra0;
    *(bf16x8*)(AsB + 4096 + tid * 16) = ra1;
    *(bf16x8*)(BsB + tid * 16)        = rb0;
    *(bf16x8*)(BsB + 4096 + tid * 16) = rb1;
    if (nk > 1) {
        ra0 = *(const bf16x8*)(Arow + GBK);
        ra1 = *(const bf16x8*)(Arow + a2 + GBK);
        rb0 = *(const bf16x8*)(Brow + GBK);
        rb1 = *(const bf16x8*)(Brow + b2 + GBK);
    }
    __syncthreads();

    for (int ki = 0; ki < nk; ki++) {
        int ib = ki & 1;
        if (ki + 1 < nk) {
            char* An = AsB + (1 - ib) * 8192;
            char* Bn = BsB + (1 - ib) * 8192;
            *(bf16x8*)(An + tid * 16)        = ra0;
            *(bf16x8*)(An + 4096 + tid * 16) = ra1;
            *(bf16x8*)(Bn + tid * 16)        = rb0;
            *(bf16x8*)(Bn + 4096 + tid * 16) = rb1;
        }
        if (ki + 2 < nk) {
            int koff = (ki + 2) * GBK;
            ra0 = *(const bf16x8*)(Arow + koff);
            ra1 = *(const bf16x8*)(Arow + a2 + koff);
            rb0 = *(const bf16x8*)(Brow + koff);
            rb1 = *(const bf16x8*)(Brow + b2 + koff);
        }
        char* Ac = AsB + ib * 8192;
        char* Bc = BsB + ib * 8192;

        bf16x8 af[4], bfr[4];
#pragma unroll
        for (int mi = 0; mi < 4; mi++)
            af[mi] = *(const bf16x8*)(Ac + ((wm * 64 + mi * 16 + lr) * GBK + lq * 8) * 2);
#pragma unroll
        for (int ni = 0; ni < 4; ni++)
            bfr[ni] = *(const bf16x8*)(Bc + ((wn * 64 + ni * 16 + lr) * GBK + lq * 8) * 2);
#pragma unroll
        for (int mi = 0; mi < 4; mi++)
#pragma unroll
            for (int ni = 0; ni < 4; ni++)
                acc[mi][ni] = __builtin_amdgcn_mfma_f32_16x16x32_bf16(
                    af[mi], bfr[ni], acc[mi][ni], 0, 0, 0);
        __syncthreads();
    }

    int m0 = mt * GBM, n0 = nt * GBN;
#pragma unroll
    for (int mi = 0; mi < 4; mi++) {
#pragma unroll
        for (int ni = 0; ni < 4; ni++) {
            int colL = n0 + wn * 64 + ni * 16 + lr;
#pragma unroll
            for (int r = 0; r < 4; r++) {
                int rowL = m0 + wm * 64 + mi * 16 + lq * 4 + r;
                float val = acc[mi][ni][r];
                if (MODE == 5) {
                    val += bias[colL];
                    if (colL < 768) {
                        bf16* Cp = (bf16*)Cv;
                        Cp[(long)rowL * 768 + colL] = (bf16)val;
                    } else {
                        bf16* Cp = (bf16*)Cv2;
                        long addr = (long)(rowL >> 8) * (E * T) + (long)(colL - 768) * T + (rowL & 255);
                        Cp[addr] = (bf16)val;
                    }
                } else if (MODE == 1) {
                    float* Cp = (float*)Cv;
                    long idx = (long)rowL * ldc + colL;
                    Cp[idx] = Cp[idx] + val + bias[colL];
                } else if (MODE == 4) {
                    if (colL < Nvalid) {
                        float* Cp = (float*)Cv;
                        Cp[(long)rowL * ldc + colL] = val + bias[colL];
                    }
                } else {
                    if (colL < Nvalid) {
                        if (bias) val += bias[colL];
                        if (relu) val = fmaxf(val, 0.f);
                        bf16* Cp = (bf16*)Cv + (long)bb * sCb + (long)bh * sCh;
                        Cp[(long)rowL * ldc + colL] = (bf16)val;
                    }
                }
            }
        }
    }
}

// ---------------- fused causal attention (LDS-staged K/V) ----------------
// grid: (b, h, qt) = BB*NH*4 blocks of 256 threads (4 waves).
// K[256x64] and V^T[64x256] staged coalesced into padded LDS; all MFMA
// fragments read from LDS. P reuses the Ks region after a barrier.
__global__ __launch_bounds__(256) void k_attn(
    const bf16* __restrict__ qk, const bf16* __restrict__ vt,
    bf16* __restrict__ o)
{
    // XCD swizzle: the 4 qt-blocks of one (b,h) share K/V -> same XCD L2.
    int nb = gridDim.x;
    int per = nb >> 3;
    int bphys = blockIdx.x;
    int bid = (bphys & 7) * per + (bphys >> 3);

    int qt = bid & 3; bid >>= 2;
    int h = bid % NH; int b = bid / NH;
    int tid = threadIdx.x;
    int lane = tid & 63;
    int w = tid >> 6;
    int lq = lane >> 4;     // 0..3
    int lr = lane & 15;

    __shared__ __align__(16) bf16 Ks[256 * 72];   // K rows padded 64->72 (2-way banks); reused for P
    __shared__ __align__(16) bf16 Vs[64 * 264];   // V^T rows padded 256->264

    const bf16* qbase = qk + (long)(b * T + qt * 64 + w * 16) * 768 + h * 64;
    const bf16* kbase = qk + (long)(b * T) * 768 + 384 + h * 64;
    const bf16* vbase = vt + ((long)b * E + h * 64) * T;

    // stage K: 256 rows x 64 cols = 2048 chunks of 16B (8 per row)
#pragma unroll
    for (int i = 0; i < 8; i++) {
        int idx = i * 256 + tid;
        int row = idx >> 3, off = (idx & 7) * 8;
        *(bf16x8*)(&Ks[row * 72 + off]) = *(const bf16x8*)(kbase + (long)row * 768 + off);
    }
    // stage V: 64 rows x 256 cols = 2048 chunks of 16B (32 per row)
#pragma unroll
    for (int i = 0; i < 8; i++) {
        int idx = i * 256 + tid;
        int row = idx >> 5, off = (idx & 31) * 8;
        *(bf16x8*)(&Vs[row * 264 + off]) = *(const bf16x8*)(vbase + (long)row * 256 + off);
    }

    // Q A-fragments direct from global (2 loads/wave)
    bf16x8 aq0 = *(const bf16x8*)(qbase + (long)lr * 768 + lq * 8);
    bf16x8 aq1 = *(const bf16x8*)(qbase + (long)lr * 768 + 32 + lq * 8);

    __syncthreads();

    const int ntmax = qt * 4 + 3;
    floatx4 zero = {0.f, 0.f, 0.f, 0.f};
    floatx4 s[16];
#pragma unroll
    for (int nt = 0; nt < 16; nt++) s[nt] = zero;

#pragma unroll
    for (int nt = 0; nt < 16; nt++) {
        if (nt <= ntmax) {
            const bf16* kp = &Ks[(nt * 16 + lr) * 72 + lq * 8];
            bf16x8 b0 = *(const bf16x8*)(kp);
            bf16x8 b1 = *(const bf16x8*)(kp + 32);
            s[nt] = __builtin_amdgcn_mfma_f32_16x16x32_bf16(aq0, b0, s[nt], 0, 0, 0);
            s[nt] = __builtin_amdgcn_mfma_f32_16x16x32_bf16(aq1, b1, s[nt], 0, 0, 0);
        }
    }

    // scale + causal mask + row max
    int trow0 = qt * 64 + w * 16 + lq * 4;
    float m4[4] = {-3e38f, -3e38f, -3e38f, -3e38f};
#pragma unroll
    for (int nt = 0; nt < 16; nt++) {
        if (nt <= ntmax) {
            int tc = nt * 16 + lr;
#pragma unroll
            for (int r = 0; r < 4; r++) {
                float v = s[nt][r] * 0.125f;
                if (tc > trow0 + r) v = -3e38f;
                s[nt][r] = v;
                m4[r] = fmaxf(m4[r], v);
            }
        }
    }
#pragma unroll
    for (int r = 0; r < 4; r++) {
#pragma unroll
        for (int off = 1; off < 16; off <<= 1)
            m4[r] = fmaxf(m4[r], __shfl_xor(m4[r], off, 64));
    }

    // exp in registers + row sums (keep P in regs until Ks is free)
    float l4[4] = {0.f, 0.f, 0.f, 0.f};
#pragma unroll
    for (int nt = 0; nt < 16; nt++) {
        if (nt <= ntmax) {
#pragma unroll
            for (int r = 0; r < 4; r++) {
                float pv = __expf(s[nt][r] - m4[r]);
                l4[r] += pv;
                s[nt][r] = pv;
            }
        }
    }
#pragma unroll
    for (int r = 0; r < 4; r++) {
#pragma unroll
        for (int off = 1; off < 16; off <<= 1)
            l4[r] += __shfl_xor(l4[r], off, 64);
    }

    __syncthreads();   // all waves done reading Ks -> reuse region for P

    // write P (wave-private slice of Ks region), C-layout -> A-layout
    bf16* P = Ks + w * (16 * 264);
#pragma unroll
    for (int nt = 0; nt < 16; nt++) {
        if (nt <= ntmax) {
#pragma unroll
            for (int r = 0; r < 4; r++)
                P[(lq * 4 + r) * 264 + nt * 16 + lr] = (bf16)s[nt][r];
        }
    }

    // O = P @ V from LDS (valid k-tiles only)
    floatx4 oacc[4];
#pragma unroll
    for (int nd = 0; nd < 4; nd++) oacc[nd] = zero;
    const int kkmax = 2 * (qt + 1);
#pragma unroll
    for (int kk = 0; kk < 8; kk++) {
        if (kk < kkmax) {
            bf16x8 ap = *(const bf16x8*)(&P[lr * 264 + kk * 32 + lq * 8]);
#pragma unroll
            for (int nd = 0; nd < 4; nd++) {
                bf16x8 bv = *(const bf16x8*)(&Vs[(nd * 16 + lr) * 264 + kk * 32 + lq * 8]);
                oacc[nd] = __builtin_amdgcn_mfma_f32_16x16x32_bf16(ap, bv, oacc[nd], 0, 0, 0);
            }
        }
    }

    // epilogue: scale by 1/l and store
#pragma unroll
    for (int r = 0; r < 4; r++) {
        float inv = 1.0f / l4[r];
        long rowg = (long)b * T + trow0 + r;
#pragma unroll
        for (int nd = 0; nd < 4; nd++) {
            o[rowg * E + h * 64 + nd * 16 + lr] = (bf16)(oacc[nd][r] * inv);
        }
    }
}

// ---------------- weight transpose f32 -> bf16 (+zero-pad rows) ----------------
__global__ void k_transpose(const float* __restrict__ W, bf16* __restrict__ Wt,
                            int K, int N, int NPAD) {
    long idx = (long)blockIdx.x * 256 + threadIdx.x;
    long per = (long)NPAD * K;
    int l = (int)(idx / per);
    long r = idx - (long)l * per;
    int n = (int)(r / K);
    int k = (int)(r - (long)n * K);
    Wt[idx] = (n < N) ? (bf16)W[((long)l * K + k) * N + n] : (bf16)0.0f;
}

// ---------------- fused QKV weight transpose: [L][1152][384] ----------------
__global__ void k_transpose_qkv(const float* __restrict__ Wq, const float* __restrict__ Wk,
                                const float* __restrict__ Wv, bf16* __restrict__ Wt) {
    long idx = (long)blockIdx.x * 256 + threadIdx.x;
    long per = (long)1152 * E;
    int l = (int)(idx / per);
    long r = idx - (long)l * per;
    int n = (int)(r / E);
    int k = (int)(r - (long)n * E);
    const float* src;
    int nn;
    if (n < 384)      { src = Wq; nn = n; }
    else if (n < 768) { src = Wk; nn = n - 384; }
    else              { src = Wv; nn = n - 768; }
    Wt[idx] = (bf16)src[((long)l * E + k) * E + nn];
}

// ---------------- fused QKV bias concat: [L][1152] f32 ----------------
__global__ void k_bias_qkv(const float* __restrict__ bq, const float* __restrict__ bk,
                           const float* __restrict__ bv, float* __restrict__ bqkv) {
    int idx = blockIdx.x * 256 + threadIdx.x;
    int l = idx / 1152;
    int j = idx - l * 1152;
    const float* src;
    int jj;
    if (j < 384)      { src = bq; jj = j; }
    else if (j < 768) { src = bk; jj = j - 384; }
    else              { src = bv; jj = j - 768; }
    bqkv[idx] = src[l * E + jj];
}

// ---------------- embedding + positional (f32) ----------------
__global__ void k_embed(const int* __restrict__ tokens, const float* __restrict__ pos,
                        const float* __restrict__ emb, float* __restrict__ x) {
    long idx = (long)blockIdx.x * 256 + threadIdx.x;
    int e = (int)(idx % E);
    long bt = idx / E;
    int t = (int)(bt % T);
    int tok = tokens[bt];
    x[idx] = emb[(long)tok * E + e] + pos[(long)t * E + e];
}

// ---------------- layernorm: f32 in -> bf16 out (wave per row) ----------------
__global__ void k_ln(const float* __restrict__ x, const float* __restrict__ g,
                     const float* __restrict__ b, bf16* __restrict__ h) {
    int row = blockIdx.x * 4 + (threadIdx.x >> 6);
    int lane = threadIdx.x & 63;
    const float* xr = x + (long)row * E;
    float v[6];
    float s = 0.f;
#pragma unroll
    for (int i = 0; i < 6; i++) { v[i] = xr[lane + 64 * i]; s += v[i]; }
#pragma unroll
    for (int o = 1; o < 64; o <<= 1) s += __shfl_xor(s, o, 64);
    float mu = s * (1.0f / E);
    float q = 0.f;
#pragma unroll
    for (int i = 0; i < 6; i++) { float d = v[i] - mu; q += d * d; }
#pragma unroll
    for (int o = 1; o < 64; o <<= 1) q += __shfl_xor(q, o, 64);
    float rs = rsqrtf(q * (1.0f / E) + 1e-5f);
    bf16* hr = h + (long)row * E;
#pragma unroll
    for (int i = 0; i < 6; i++) {
        int c = lane + 64 * i;
        hr[c] = (bf16)((v[i] - mu) * rs * g[c] + b[c]);
    }
}

// ---------------- f32 -> bf16 convert ----------------
__global__ void k_cvt(const float* __restrict__ x, bf16* __restrict__ y) {
    long i = (long)blockIdx.x * 256 + threadIdx.x;
    y[i] = (bf16)x[i];
}

// ---------------- launcher ----------------
extern "C" void kernel_launch(void* const* d_in, const int* in_sizes, int n_in,
                              void* d_out, int out_size, void* d_ws, size_t ws_size,
                              hipStream_t stream) {
    const int*   tokens = (const int*)d_in[0];
    const float* pos  = (const float*)d_in[1];
    const float* emb  = (const float*)d_in[2];
    const float* Wq   = (const float*)d_in[3];
    const float* bq   = (const float*)d_in[4];
    const float* Wk   = (const float*)d_in[5];
    const float* bk   = (const float*)d_in[6];
    const float* Wv   = (const float*)d_in[7];
    const float* bv   = (const float*)d_in[8];
    const float* Wo   = (const float*)d_in[9];
    const float* bo   = (const float*)d_in[10];
    const float* g1   = (const float*)d_in[11];
    const float* be1  = (const float*)d_in[12];
    const float* W1   = (const float*)d_in[13];
    const float* c1   = (const float*)d_in[14];
    const float* W2   = (const float*)d_in[15];
    const float* c2   = (const float*)d_in[16];
    const float* g2   = (const float*)d_in[17];
    const float* be2  = (const float*)d_in[18];
    const float* Wl   = (const float*)d_in[19];
    const float* bl   = (const float*)d_in[20];

    // ---- workspace layout (~198 MB peak; unchanged from r10 which passed) ----
    char* p = (char*)d_ws;
    float* x = (float*)p;  p += (long)MTOT * E * 4;          // residual (f32)
    bf16* h  = (bf16*)p;   p += (long)MTOT * E * 2;          // LN out / o (alias)
    bf16* qk = (bf16*)p;   p += (long)MTOT * 768 * 2;        // fused Q|K
    bf16* vt = (bf16*)p;   p += (long)BB * E * T * 2;        // V^T per (seq,head)
    bf16* SP = (bf16*)p;   p += (long)CB * NH * T * T * 2;   // kept only for mid alias span
    bf16* WqkvT = (bf16*)p; p += (long)NL * 1152 * E * 2;
    bf16* WoT = (bf16*)p;  p += (long)NL * E * E * 2;
    bf16* W1T = (bf16*)p;  p += (long)NL * DFF * E * 2;
    bf16* W2T = (bf16*)p;  p += (long)NL * E * DFF * 2;
    bf16* WlT = (bf16*)p;  p += (long)128 * E * 2;
    float* bqkv = (float*)p; p += (long)NL * 1152 * 4;
    bf16* mid = qk;          // alias: qk+vt+SP = 100.66 MB = MTOT*DFF*2 exactly
    bf16* o   = h;           // alias: h dead after QKV GEMM
    (void)SP;

    // ---- setup (once per call) ----
    k_transpose_qkv<<<(NL * 1152 * E) / 256, 256, 0, stream>>>(Wq, Wk, Wv, WqkvT);
    k_transpose<<<(NL * E * E) / 256, 256, 0, stream>>>(Wo, WoT, E, E, E);
    k_transpose<<<(NL * DFF * E) / 256, 256, 0, stream>>>(W1, W1T, E, DFF, DFF);
    k_transpose<<<(NL * E * DFF) / 256, 256, 0, stream>>>(W2, W2T, DFF, E, E);
    k_transpose<<<(128 * E) / 256, 256, 0, stream>>>(Wl, WlT, E, NV, 128);
    k_bias_qkv<<<(NL * 1152) / 256, 256, 0, stream>>>(bq, bk, bv, bqkv);

    // ---- embedding ----
    k_embed<<<(MTOT * E) / 256, 256, 0, stream>>>(tokens, pos, emb, x);

    for (int l = 0; l < NL; l++) {
        // LN1 full-M
        k_ln<<<MTOT / 4, 256, 0, stream>>>(x, g1 + l * E, be1 + l * E, h);
        // fused QKV: M=32768, N=1152, K=384
        k_gemm<5><<<256 * 9, 256, 0, stream>>>(h, 0, 0, E, WqkvT + (long)l * 1152 * E, 0, 0, E,
                                               bqkv + l * 1152, qk, vt, 0, 0, 0,
                                               256, 9, 1152, E, 1, 1.0f, 0);
        // fused causal attention: one dispatch
        k_attn<<<BB * NH * 4, 256, 0, stream>>>(qk, vt, o);
        // x += O @ Wo + bo   (f32 in-place, full-M)
        k_gemm<1><<<256 * 3, 256, 0, stream>>>(o, 0, 0, E, WoT + (long)l * E * E, 0, 0, E,
                                               bo + l * E, x, nullptr, 0, 0, E,
                                               256, 3, E, E, 1, 1.0f, 0);
        // LN2 full-M
        k_ln<<<MTOT / 4, 256, 0, stream>>>(x, g2 + l * E, be2 + l * E, h);
        // mid = relu(h @ W1 + c1)   (M=32768, N=1536)
        k_gemm<0><<<256 * 12, 256, 0, stream>>>(h, 0, 0, E, W1T + (long)l * DFF * E, 0, 0, E,
                                                c1 + l * DFF, mid, nullptr, 0, 0, DFF,
                                                256, 12, DFF, E, 1, 1.0f, 1);
        // x += mid @ W2 + c2   (K=1536)
        k_gemm<1><<<256 * 3, 256, 0, stream>>>(mid, 0, 0, DFF, W2T + (long)l * E * DFF, 0, 0, DFF,
                                               c2 + l * E, x, nullptr, 0, 0, E,
                                               256, 3, E, DFF, 1, 1.0f, 0);
    }

    // logits = x_bf16 @ Wl + bl  (N=65 masked from 128), f32 out, full-M
    k_cvt<<<(MTOT * E) / 256, 256, 0, stream>>>(x, h);
    k_gemm<4><<<256 * 1, 256, 0, stream>>>(h, 0, 0, E, WlT, 0, 0, E,
                                           bl, d_out, nullptr, 0, 0, NV,
                                           256, 1, NV, E, 1, 1.0f, 0);
}

// Round 12
// 2133.441 us; speedup vs baseline: 2.1867x; 1.0411x over previous
//
#include <hip/hip_runtime.h>
#include <hip/hip_bf16.h>
#include <stdint.h>

// ---------------- problem constants ----------------
constexpr int E   = 384;
constexpr int DFF = 1536;
constexpr int NH  = 6;
constexpr int HD  = 64;
constexpr int T   = 256;
constexpr int NL  = 6;
constexpr int NV  = 65;
constexpr int BB  = 128;
constexpr int MTOT = BB * T;           // 32768 rows
constexpr int CB  = 32;                // (kept for ws layout compatibility)

typedef __bf16 bf16;
typedef __attribute__((ext_vector_type(8))) __bf16 bf16x8;
typedef __attribute__((ext_vector_type(4))) float floatx4;

// ---------------- generic bf16 GEMM: C = A[M,K] @ Bt[N,K]^T ----------------
// Two-step staging pipeline (prefetch distance 2): reg-load tile k+2,
// ds_write tile k+1, compute tile k from LDS.
// LDS row stride 80 B (vs 64) -> b128 fragment reads are 2-way bank-aliased
// (free) instead of 8-way.
// MODE 0: bf16 out (+bias opt, +relu opt, N-mask via Nvalid)
// MODE 1: bf16 residual in-place: C[r,c] += acc + bias
// MODE 4: f32 out with bias + N-mask (final logits)
// MODE 5: fused QKV: cols 0..767 -> qk row-major (ld 768); cols 768..1151 ->
//         vt[(row>>8)*(E*T) + (col-768)*T + (row&255)]  (V transposed store)
#define GBM 128
#define GBN 128
#define GBK 32
#define LROW 80                        // LDS row stride in bytes (64 data + 16 pad)
#define LBUF (GBM * LROW)              // 10240 B per buffer

template <int MODE>
__global__ __launch_bounds__(256) void k_gemm(
    const bf16* __restrict__ A, long sAb, long sAh, int lda,
    const bf16* __restrict__ Bt, long sBb, long sBh, int ldb,
    const float* __restrict__ bias,
    void* __restrict__ Cv, void* __restrict__ Cv2, long sCb, long sCh, int ldc,
    int Mtiles, int Ntiles, int Nvalid, int K,
    int bdiv, float scale, int relu)
{
    __shared__ __align__(16) char AsB[2 * LBUF];   // 2 x 10 KB
    __shared__ __align__(16) char BsB[2 * LBUF];

    // XCD swizzle: all N-tiles of an M-tile land on one XCD's L2.
    int nb = gridDim.x;
    int per = nb >> 3;
    int bphys = blockIdx.x;
    int bid = (bphys & 7) * per + (bphys >> 3);

    int nt = bid % Ntiles; bid /= Ntiles;
    int mt = bid % Mtiles;
    int bat = bid / Mtiles;
    int bb = bat / bdiv, bh = bat - bb * bdiv;

    const bf16* Ab = A + (long)bb * sAb + (long)bh * sAh + (long)mt * GBM * lda;
    const bf16* Bb = Bt + (long)bb * sBb + (long)bh * sBh + (long)nt * GBN * ldb;

    int tid = threadIdx.x;
    int lane = tid & 63;
    int wid = tid >> 6;
    int wm = wid >> 1, wn = wid & 1;
    int lq = lane >> 4, lr = lane & 15;

    int srow = tid >> 2;            // 0..63
    int skc  = (tid & 3) * 8;       // k element offset 0,8,16,24

    const bf16* Arow = Ab + (long)srow * lda + skc;
    const bf16* Brow = Bb + (long)srow * ldb + skc;
    const long a2 = 64 * (long)lda;
    const long b2 = 64 * (long)ldb;

    // LDS staging addresses (row-padded)
    const int w0 = srow * LROW + (tid & 3) * 16;
    const int w1 = (srow + 64) * LROW + (tid & 3) * 16;

    floatx4 zero = {0.f, 0.f, 0.f, 0.f};
    floatx4 acc[4][4];
#pragma unroll
    for (int i = 0; i < 4; i++)
#pragma unroll
        for (int j = 0; j < 4; j++) acc[i][j] = zero;

    int nk = K / GBK;

    // prologue: tile0 -> regs -> buf0; tile1 -> regs
    bf16x8 ra0 = *(const bf16x8*)(Arow);
    bf16x8 ra1 = *(const bf16x8*)(Arow + a2);
    bf16x8 rb0 = *(const bf16x8*)(Brow);
    bf16x8 rb1 = *(const bf16x8*)(Brow + b2);
    *(bf16x8*)(AsB + w0) = ra0;
    *(bf16x8*)(AsB + w1) = ra1;
    *(bf16x8*)(BsB + w0) = rb0;
    *(bf16x8*)(BsB + w1) = rb1;
    if (nk > 1) {
        ra0 = *(const bf16x8*)(Arow + GBK);
        ra1 = *(const bf16x8*)(Arow + a2 + GBK);
        rb0 = *(const bf16x8*)(Brow + GBK);
        rb1 = *(const bf16x8*)(Brow + b2 + GBK);
    }
    __syncthreads();

    for (int ki = 0; ki < nk; ki++) {
        int ib = ki & 1;
        if (ki + 1 < nk) {
            char* An = AsB + (1 - ib) * LBUF;
            char* Bn = BsB + (1 - ib) * LBUF;
            *(bf16x8*)(An + w0) = ra0;
            *(bf16x8*)(An + w1) = ra1;
            *(bf16x8*)(Bn + w0) = rb0;
            *(bf16x8*)(Bn + w1) = rb1;
        }
        if (ki + 2 < nk) {
            int koff = (ki + 2) * GBK;
            ra0 = *(const bf16x8*)(Arow + koff);
            ra1 = *(const bf16x8*)(Arow + a2 + koff);
            rb0 = *(const bf16x8*)(Brow + koff);
            rb1 = *(const bf16x8*)(Brow + b2 + koff);
        }
        char* Ac = AsB + ib * LBUF;
        char* Bc = BsB + ib * LBUF;

        bf16x8 af[4], bfr[4];
#pragma unroll
        for (int mi = 0; mi < 4; mi++)
            af[mi] = *(const bf16x8*)(Ac + (wm * 64 + mi * 16 + lr) * LROW + lq * 16);
#pragma unroll
        for (int ni = 0; ni < 4; ni++)
            bfr[ni] = *(const bf16x8*)(Bc + (wn * 64 + ni * 16 + lr) * LROW + lq * 16);
#pragma unroll
        for (int mi = 0; mi < 4; mi++)
#pragma unroll
            for (int ni = 0; ni < 4; ni++)
                acc[mi][ni] = __builtin_amdgcn_mfma_f32_16x16x32_bf16(
                    af[mi], bfr[ni], acc[mi][ni], 0, 0, 0);
        __syncthreads();
    }

    int m0 = mt * GBM, n0 = nt * GBN;
#pragma unroll
    for (int mi = 0; mi < 4; mi++) {
#pragma unroll
        for (int ni = 0; ni < 4; ni++) {
            int colL = n0 + wn * 64 + ni * 16 + lr;
#pragma unroll
            for (int r = 0; r < 4; r++) {
                int rowL = m0 + wm * 64 + mi * 16 + lq * 4 + r;
                float val = acc[mi][ni][r];
                if (MODE == 5) {
                    val += bias[colL];
                    if (colL < 768) {
                        bf16* Cp = (bf16*)Cv;
                        Cp[(long)rowL * 768 + colL] = (bf16)val;
                    } else {
                        bf16* Cp = (bf16*)Cv2;
                        long addr = (long)(rowL >> 8) * (E * T) + (long)(colL - 768) * T + (rowL & 255);
                        Cp[addr] = (bf16)val;
                    }
                } else if (MODE == 1) {
                    bf16* Cp = (bf16*)Cv;
                    long idx = (long)rowL * ldc + colL;
                    Cp[idx] = (bf16)((float)Cp[idx] + val + bias[colL]);
                } else if (MODE == 4) {
                    if (colL < Nvalid) {
                        float* Cp = (float*)Cv;
                        Cp[(long)rowL * ldc + colL] = val + bias[colL];
                    }
                } else {
                    if (colL < Nvalid) {
                        if (bias) val += bias[colL];
                        if (relu) val = fmaxf(val, 0.f);
                        bf16* Cp = (bf16*)Cv + (long)bb * sCb + (long)bh * sCh;
                        Cp[(long)rowL * ldc + colL] = (bf16)val;
                    }
                }
            }
        }
    }
}

// ---------------- fused causal attention (LDS-staged K/V) ----------------
__global__ __launch_bounds__(256) void k_attn(
    const bf16* __restrict__ qk, const bf16* __restrict__ vt,
    bf16* __restrict__ o)
{
    int nb = gridDim.x;
    int per = nb >> 3;
    int bphys = blockIdx.x;
    int bid = (bphys & 7) * per + (bphys >> 3);

    int qt = bid & 3; bid >>= 2;
    int h = bid % NH; int b = bid / NH;
    int tid = threadIdx.x;
    int lane = tid & 63;
    int w = tid >> 6;
    int lq = lane >> 4;     // 0..3
    int lr = lane & 15;

    __shared__ __align__(16) bf16 Ks[256 * 72];   // K rows padded; reused for P
    __shared__ __align__(16) bf16 Vs[64 * 264];   // V^T rows padded

    const bf16* qbase = qk + (long)(b * T + qt * 64 + w * 16) * 768 + h * 64;
    const bf16* kbase = qk + (long)(b * T) * 768 + 384 + h * 64;
    const bf16* vbase = vt + ((long)b * E + h * 64) * T;

#pragma unroll
    for (int i = 0; i < 8; i++) {
        int idx = i * 256 + tid;
        int row = idx >> 3, off = (idx & 7) * 8;
        *(bf16x8*)(&Ks[row * 72 + off]) = *(const bf16x8*)(kbase + (long)row * 768 + off);
    }
#pragma unroll
    for (int i = 0; i < 8; i++) {
        int idx = i * 256 + tid;
        int row = idx >> 5, off = (idx & 31) * 8;
        *(bf16x8*)(&Vs[row * 264 + off]) = *(const bf16x8*)(vbase + (long)row * 256 + off);
    }

    bf16x8 aq0 = *(const bf16x8*)(qbase + (long)lr * 768 + lq * 8);
    bf16x8 aq1 = *(const bf16x8*)(qbase + (long)lr * 768 + 32 + lq * 8);

    __syncthreads();

    const int ntmax = qt * 4 + 3;
    floatx4 zero = {0.f, 0.f, 0.f, 0.f};
    floatx4 s[16];
#pragma unroll
    for (int nt = 0; nt < 16; nt++) s[nt] = zero;

#pragma unroll
    for (int nt = 0; nt < 16; nt++) {
        if (nt <= ntmax) {
            const bf16* kp = &Ks[(nt * 16 + lr) * 72 + lq * 8];
            bf16x8 b0 = *(const bf16x8*)(kp);
            bf16x8 b1 = *(const bf16x8*)(kp + 32);
            s[nt] = __builtin_amdgcn_mfma_f32_16x16x32_bf16(aq0, b0, s[nt], 0, 0, 0);
            s[nt] = __builtin_amdgcn_mfma_f32_16x16x32_bf16(aq1, b1, s[nt], 0, 0, 0);
        }
    }

    int trow0 = qt * 64 + w * 16 + lq * 4;
    float m4[4] = {-3e38f, -3e38f, -3e38f, -3e38f};
#pragma unroll
    for (int nt = 0; nt < 16; nt++) {
        if (nt <= ntmax) {
            int tc = nt * 16 + lr;
#pragma unroll
            for (int r = 0; r < 4; r++) {
                float v = s[nt][r] * 0.125f;
                if (tc > trow0 + r) v = -3e38f;
                s[nt][r] = v;
                m4[r] = fmaxf(m4[r], v);
            }
        }
    }
#pragma unroll
    for (int r = 0; r < 4; r++) {
#pragma unroll
        for (int off = 1; off < 16; off <<= 1)
            m4[r] = fmaxf(m4[r], __shfl_xor(m4[r], off, 64));
    }

    float l4[4] = {0.f, 0.f, 0.f, 0.f};
#pragma unroll
    for (int nt = 0; nt < 16; nt++) {
        if (nt <= ntmax) {
#pragma unroll
            for (int r = 0; r < 4; r++) {
                float pv = __expf(s[nt][r] - m4[r]);
                l4[r] += pv;
                s[nt][r] = pv;
            }
        }
    }
#pragma unroll
    for (int r = 0; r < 4; r++) {
#pragma unroll
        for (int off = 1; off < 16; off <<= 1)
            l4[r] += __shfl_xor(l4[r], off, 64);
    }

    __syncthreads();   // Ks fully consumed -> reuse for P

    bf16* P = Ks + w * (16 * 264);
#pragma unroll
    for (int nt = 0; nt < 16; nt++) {
        if (nt <= ntmax) {
#pragma unroll
            for (int r = 0; r < 4; r++)
                P[(lq * 4 + r) * 264 + nt * 16 + lr] = (bf16)s[nt][r];
        }
    }

    floatx4 oacc[4];
#pragma unroll
    for (int nd = 0; nd < 4; nd++) oacc[nd] = zero;
    const int kkmax = 2 * (qt + 1);
#pragma unroll
    for (int kk = 0; kk < 8; kk++) {
        if (kk < kkmax) {
            bf16x8 ap = *(const bf16x8*)(&P[lr * 264 + kk * 32 + lq * 8]);
#pragma unroll
            for (int nd = 0; nd < 4; nd++) {
                bf16x8 bv = *(const bf16x8*)(&Vs[(nd * 16 + lr) * 264 + kk * 32 + lq * 8]);
                oacc[nd] = __builtin_amdgcn_mfma_f32_16x16x32_bf16(ap, bv, oacc[nd], 0, 0, 0);
            }
        }
    }

#pragma unroll
    for (int r = 0; r < 4; r++) {
        float inv = 1.0f / l4[r];
        long rowg = (long)b * T + trow0 + r;
#pragma unroll
        for (int nd = 0; nd < 4; nd++) {
            o[rowg * E + h * 64 + nd * 16 + lr] = (bf16)(oacc[nd][r] * inv);
        }
    }
}

// ---------------- weight transpose f32 -> bf16 (+zero-pad rows) ----------------
__global__ void k_transpose(const float* __restrict__ W, bf16* __restrict__ Wt,
                            int K, int N, int NPAD) {
    long idx = (long)blockIdx.x * 256 + threadIdx.x;
    long per = (long)NPAD * K;
    int l = (int)(idx / per);
    long r = idx - (long)l * per;
    int n = (int)(r / K);
    int k = (int)(r - (long)n * K);
    Wt[idx] = (n < N) ? (bf16)W[((long)l * K + k) * N + n] : (bf16)0.0f;
}

// ---------------- fused QKV weight transpose: [L][1152][384] ----------------
__global__ void k_transpose_qkv(const float* __restrict__ Wq, const float* __restrict__ Wk,
                                const float* __restrict__ Wv, bf16* __restrict__ Wt) {
    long idx = (long)blockIdx.x * 256 + threadIdx.x;
    long per = (long)1152 * E;
    int l = (int)(idx / per);
    long r = idx - (long)l * per;
    int n = (int)(r / E);
    int k = (int)(r - (long)n * E);
    const float* src;
    int nn;
    if (n < 384)      { src = Wq; nn = n; }
    else if (n < 768) { src = Wk; nn = n - 384; }
    else              { src = Wv; nn = n - 768; }
    Wt[idx] = (bf16)src[((long)l * E + k) * E + nn];
}

// ---------------- fused QKV bias concat: [L][1152] f32 ----------------
__global__ void k_bias_qkv(const float* __restrict__ bq, const float* __restrict__ bk,
                           const float* __restrict__ bv, float* __restrict__ bqkv) {
    int idx = blockIdx.x * 256 + threadIdx.x;
    int l = idx / 1152;
    int j = idx - l * 1152;
    const float* src;
    int jj;
    if (j < 384)      { src = bq; jj = j; }
    else if (j < 768) { src = bk; jj = j - 384; }
    else              { src = bv; jj = j - 768; }
    bqkv[idx] = src[l * E + jj];
}

// ---------------- embedding + positional -> bf16 residual ----------------
__global__ void k_embed(const int* __restrict__ tokens, const float* __restrict__ pos,
                        const float* __restrict__ emb, bf16* __restrict__ x) {
    long idx = (long)blockIdx.x * 256 + threadIdx.x;
    int e = (int)(idx % E);
    long bt = idx / E;
    int t = (int)(bt % T);
    int tok = tokens[bt];
    x[idx] = (bf16)(emb[(long)tok * E + e] + pos[(long)t * E + e]);
}

// ---------------- layernorm: bf16 in -> bf16 out (wave per row) ----------------
__global__ void k_ln(const bf16* __restrict__ x, const float* __restrict__ g,
                     const float* __restrict__ b, bf16* __restrict__ h) {
    int row = blockIdx.x * 4 + (threadIdx.x >> 6);
    int lane = threadIdx.x & 63;
    const bf16* xr = x + (long)row * E;
    float v[6];
    float s = 0.f;
#pragma unroll
    for (int i = 0; i < 6; i++) { v[i] = (float)xr[lane + 64 * i]; s += v[i]; }
#pragma unroll
    for (int o = 1; o < 64; o <<= 1) s += __shfl_xor(s, o, 64);
    float mu = s * (1.0f / E);
    float q = 0.f;
#pragma unroll
    for (int i = 0; i < 6; i++) { float d = v[i] - mu; q += d * d; }
#pragma unroll
    for (int o = 1; o < 64; o <<= 1) q += __shfl_xor(q, o, 64);
    float rs = rsqrtf(q * (1.0f / E) + 1e-5f);
    bf16* hr = h + (long)row * E;
#pragma unroll
    for (int i = 0; i < 6; i++) {
        int c = lane + 64 * i;
        hr[c] = (bf16)((v[i] - mu) * rs * g[c] + b[c]);
    }
}

// ---------------- launcher ----------------
extern "C" void kernel_launch(void* const* d_in, const int* in_sizes, int n_in,
                              void* d_out, int out_size, void* d_ws, size_t ws_size,
                              hipStream_t stream) {
    const int*   tokens = (const int*)d_in[0];
    const float* pos  = (const float*)d_in[1];
    const float* emb  = (const float*)d_in[2];
    const float* Wq   = (const float*)d_in[3];
    const float* bq   = (const float*)d_in[4];
    const float* Wk   = (const float*)d_in[5];
    const float* bk   = (const float*)d_in[6];
    const float* Wv   = (const float*)d_in[7];
    const float* bv   = (const float*)d_in[8];
    const float* Wo   = (const float*)d_in[9];
    const float* bo   = (const float*)d_in[10];
    const float* g1   = (const float*)d_in[11];
    const float* be1  = (const float*)d_in[12];
    const float* W1   = (const float*)d_in[13];
    const float* c1   = (const float*)d_in[14];
    const float* W2   = (const float*)d_in[15];
    const float* c2   = (const float*)d_in[16];
    const float* g2   = (const float*)d_in[17];
    const float* be2  = (const float*)d_in[18];
    const float* Wl   = (const float*)d_in[19];
    const float* bl   = (const float*)d_in[20];

    // ---- workspace layout (~173 MB peak) ----
    char* p = (char*)d_ws;
    bf16* x  = (bf16*)p;   p += (long)MTOT * E * 2;          // residual (bf16 now)
    bf16* h  = (bf16*)p;   p += (long)MTOT * E * 2;          // LN out / o (alias)
    bf16* qk = (bf16*)p;   p += (long)MTOT * 768 * 2;        // fused Q|K
    bf16* vt = (bf16*)p;   p += (long)BB * E * T * 2;        // V^T per (seq,head)
    bf16* SP = (bf16*)p;   p += (long)CB * NH * T * T * 2;   // kept only for mid alias span
    bf16* WqkvT = (bf16*)p; p += (long)NL * 1152 * E * 2;
    bf16* WoT = (bf16*)p;  p += (long)NL * E * E * 2;
    bf16* W1T = (bf16*)p;  p += (long)NL * DFF * E * 2;
    bf16* W2T = (bf16*)p;  p += (long)NL * E * DFF * 2;
    bf16* WlT = (bf16*)p;  p += (long)128 * E * 2;
    float* bqkv = (float*)p; p += (long)NL * 1152 * 4;
    bf16* mid = qk;          // alias: qk+vt+SP = 100.66 MB = MTOT*DFF*2 exactly
    bf16* o   = h;           // alias: h dead after QKV GEMM
    (void)SP;

    // ---- setup (once per call) ----
    k_transpose_qkv<<<(NL * 1152 * E) / 256, 256, 0, stream>>>(Wq, Wk, Wv, WqkvT);
    k_transpose<<<(NL * E * E) / 256, 256, 0, stream>>>(Wo, WoT, E, E, E);
    k_transpose<<<(NL * DFF * E) / 256, 256, 0, stream>>>(W1, W1T, E, DFF, DFF);
    k_transpose<<<(NL * E * DFF) / 256, 256, 0, stream>>>(W2, W2T, DFF, E, E);
    k_transpose<<<(128 * E) / 256, 256, 0, stream>>>(Wl, WlT, E, NV, 128);
    k_bias_qkv<<<(NL * 1152) / 256, 256, 0, stream>>>(bq, bk, bv, bqkv);

    // ---- embedding ----
    k_embed<<<(MTOT * E) / 256, 256, 0, stream>>>(tokens, pos, emb, x);

    for (int l = 0; l < NL; l++) {
        // LN1 full-M
        k_ln<<<MTOT / 4, 256, 0, stream>>>(x, g1 + l * E, be1 + l * E, h);
        // fused QKV: M=32768, N=1152, K=384
        k_gemm<5><<<256 * 9, 256, 0, stream>>>(h, 0, 0, E, WqkvT + (long)l * 1152 * E, 0, 0, E,
                                               bqkv + l * 1152, qk, vt, 0, 0, 0,
                                               256, 9, 1152, E, 1, 1.0f, 0);
        // fused causal attention: one dispatch
        k_attn<<<BB * NH * 4, 256, 0, stream>>>(qk, vt, o);
        // x += O @ Wo + bo   (bf16 in-place, full-M)
        k_gemm<1><<<256 * 3, 256, 0, stream>>>(o, 0, 0, E, WoT + (long)l * E * E, 0, 0, E,
                                               bo + l * E, x, nullptr, 0, 0, E,
                                               256, 3, E, E, 1, 1.0f, 0);
        // LN2 full-M
        k_ln<<<MTOT / 4, 256, 0, stream>>>(x, g2 + l * E, be2 + l * E, h);
        // mid = relu(h @ W1 + c1)   (M=32768, N=1536)
        k_gemm<0><<<256 * 12, 256, 0, stream>>>(h, 0, 0, E, W1T + (long)l * DFF * E, 0, 0, E,
                                                c1 + l * DFF, mid, nullptr, 0, 0, DFF,
                                                256, 12, DFF, E, 1, 1.0f, 1);
        // x += mid @ W2 + c2   (K=1536)
        k_gemm<1><<<256 * 3, 256, 0, stream>>>(mid, 0, 0, DFF, W2T + (long)l * E * DFF, 0, 0, DFF,
                                               c2 + l * E, x, nullptr, 0, 0, E,
                                               256, 3, E, DFF, 1, 1.0f, 0);
    }

    // logits = x @ Wl + bl  (N=65 masked from 128), f32 out, full-M
    k_gemm<4><<<256 * 1, 256, 0, stream>>>(x, 0, 0, E, WlT, 0, 0, E,
                                           bl, d_out, nullptr, 0, 0, NV,
                                           256, 1, NV, E, 1, 1.0f, 0);
}